// Round 4
// baseline (269.224 us; speedup 1.0000x reference)
//
#include <hip/hip_runtime.h>
#include <hip/hip_bf16.h>
#include <math.h>

typedef __bf16 bf16;
typedef __bf16 bf16x8 __attribute__((ext_vector_type(8)));
typedef __bf16 bf16x4v __attribute__((ext_vector_type(4)));
typedef short s16x4 __attribute__((ext_vector_type(4)));
typedef float f32x4 __attribute__((ext_vector_type(4)));

#define GLD16(gp, lp) __builtin_amdgcn_global_load_lds( \
    (__attribute__((address_space(1))) void*)(void*)(gp), \
    (__attribute__((address_space(3))) void*)(lp), 16, 0, 0)

#define L_SEQ 2048
#define D_MODEL 2048
#define QKV_N 3072
#define HD 128
#define QSCALE 0.1275310242959836f               // (1/sqrt(128)) * log2(e)
#define LOG2E 1.4426950408889634f

// ---------------------------------------------------------------------------
// prep: fused  (a) x f32->bf16 cast  (b) Wqkv^T cast  (c) Wo^T cast
// ---------------------------------------------------------------------------
__global__ __launch_bounds__(256) void prep(const float* __restrict__ x,
                                            const float* __restrict__ Wqkv,
                                            const float* __restrict__ Wo,
                                            bf16* __restrict__ xb,
                                            bf16* __restrict__ wqkvT,
                                            bf16* __restrict__ woT) {
    __shared__ float tile[32][33];
    int bid = blockIdx.x;
    if (bid < 4096) {                       // cast x (4M elems, 4/thread)
        int idx = (bid * 256 + threadIdx.x) * 4;
        float4 f = *(const float4*)(x + idx);
        bf16x4v o;
        o.x = (bf16)f.x; o.y = (bf16)f.y; o.z = (bf16)f.z; o.w = (bf16)f.w;
        *(bf16x4v*)(xb + idx) = o;
        return;
    }
    bid -= 4096;
    const float* src; bf16* dst; long ld_s, ld_d; int bx, by;
    if (bid < 6144) { bx = bid % 96; by = bid / 96; src = Wqkv; dst = wqkvT; ld_s = QKV_N; ld_d = D_MODEL; }
    else { bid -= 6144; bx = bid & 63; by = bid >> 6; src = Wo; dst = woT; ld_s = D_MODEL; ld_d = D_MODEL; }
    const int tx = threadIdx.x & 31, ty = threadIdx.x >> 5;
    const long c = bx * 32 + tx, r0 = by * 32;
#pragma unroll
    for (int i = 0; i < 4; ++i)
        tile[ty + i * 8][tx] = src[(r0 + ty + i * 8) * ld_s + c];
    __syncthreads();
    const long c0 = bx * 32;
#pragma unroll
    for (int i = 0; i < 4; ++i)
        dst[(c0 + ty + i * 8) * ld_d + r0 + tx] = (bf16)tile[tx][ty + i * 8];
}

// ---------------------------------------------------------------------------
// gemm_qkv: 64Mx128N block, 4 waves (2Mx2N), wave tile 32x64, BK=64 dbuf.
// Grid 24x32 = 768 blocks @ 48KB LDS = 3 blocks/CU.
// ---------------------------------------------------------------------------
__global__ __launch_bounds__(256, 3) void gemm_qkv(const bf16* __restrict__ A,
                                                   const bf16* __restrict__ Bt,
                                                   bf16* __restrict__ Qb,
                                                   bf16* __restrict__ Kb,
                                                   bf16* __restrict__ Vtb) {
    constexpr int KDIM = D_MODEL;
    __shared__ __align__(16) bf16 As[2][64 * 64];
    __shared__ __align__(16) bf16 Bs[2][128 * 64];
    const int tid = threadIdx.x;
    const int wid = tid >> 6, lane = tid & 63;
    const int quad = lane >> 4, l15 = lane & 15;
    const int wm = wid & 1, wn = wid >> 1;
    const int head = blockIdx.x;
    const long m0 = (long)blockIdx.y * 64, n0 = (long)head * 128;

    f32x4 acc[2][4];
#pragma unroll
    for (int i = 0; i < 2; ++i)
#pragma unroll
        for (int j = 0; j < 4; ++j) acc[i][j] = (f32x4){0.f, 0.f, 0.f, 0.f};

    const int srow8 = lane >> 3;             // row within 8-row group
    const int schunk = lane & 7;             // LDS chunk position

    auto stage = [&](int k0, int buf) {
#pragma unroll
        for (int ii = 0; ii < 2; ++ii) {     // A tile: 64 rows
            const int rowb = wid * 16 + ii * 8;
            const int row = rowb + srow8;
            const int gcol = (schunk ^ (row & 7)) * 8;
            GLD16(A + (m0 + row) * KDIM + k0 + gcol, &As[buf][rowb * 64]);
        }
#pragma unroll
        for (int ii = 0; ii < 4; ++ii) {     // B tile: 128 rows
            const int rowb = wid * 32 + ii * 8;
            const int row = rowb + srow8;
            const int gcol = (schunk ^ (row & 7)) * 8;
            GLD16(Bt + (n0 + row) * KDIM + k0 + gcol, &Bs[buf][rowb * 64]);
        }
    };
    stage(0, 0);

    for (int k0 = 0; k0 < KDIM; k0 += 64) {
        __syncthreads();
        if (k0 + 64 < KDIM) stage(k0 + 64, ((k0 >> 6) + 1) & 1);
        const int buf = (k0 >> 6) & 1;
#pragma unroll
        for (int ks = 0; ks < 2; ++ks) {
            const int pos = ((ks * 4 + quad) ^ (l15 & 7)) * 8;
            bf16x8 af[2], bfr[4];
#pragma unroll
            for (int i = 0; i < 2; ++i)
                af[i] = *(const bf16x8*)&As[buf][(wm * 32 + i * 16 + l15) * 64 + pos];
#pragma unroll
            for (int j = 0; j < 4; ++j)
                bfr[j] = *(const bf16x8*)&Bs[buf][(j * 32 + wn * 16 + l15) * 64 + pos];
#pragma unroll
            for (int i = 0; i < 2; ++i)
#pragma unroll
                for (int j = 0; j < 4; ++j)
                    acc[i][j] = __builtin_amdgcn_mfma_f32_16x16x32_bf16(af[i], bfr[j], acc[i][j], 0, 0, 0);
        }
    }

    if (head < 20) {                                   // Q or K head: RoPE
        const float sc = head < 16 ? QSCALE : 1.0f;
        bf16* dst = head < 16 ? Qb + (long)head * L_SEQ * HD
                              : Kb + (long)(head - 16) * L_SEQ * HD;
        const int d0 = wn * 16 + l15;                  // rotate pair (j=0, j=2)
        const float freq = exp2f((float)d0 * (-10.0f / 31.0f));
        const int d1 = 32 + wn * 16 + l15;             // identity pair (j=1, j=3)
#pragma unroll
        for (int i = 0; i < 2; ++i)
#pragma unroll
            for (int r = 0; r < 4; ++r) {
                const long row = m0 + wm * 32 + i * 16 + quad * 4 + r;
                float sn, cs;
                sincosf((float)row * freq, &sn, &cs);
                const float x1 = acc[i][0][r], x2 = acc[i][2][r];
                bf16* p = dst + row * HD;
                p[d0]      = (bf16)((x1 * cs + x2 * sn) * sc);
                p[d0 + 64] = (bf16)((x2 * cs - x1 * sn) * sc);
                p[d1]      = (bf16)(acc[i][1][r] * sc);
                p[d1 + 64] = (bf16)(acc[i][3][r] * sc);
            }
    } else {                                           // V head: write V^T[d][l]
        bf16* dst = Vtb + (long)(head - 20) * HD * L_SEQ;
#pragma unroll
        for (int i = 0; i < 2; ++i) {
            const long m = m0 + wm * 32 + i * 16 + quad * 4;
#pragma unroll
            for (int j = 0; j < 4; ++j) {
                const int d = j * 32 + wn * 16 + l15;
                bf16x4v vv;
#pragma unroll
                for (int r = 0; r < 4; ++r) vv[r] = (bf16)acc[i][j][r];
                *(bf16x4v*)(dst + (long)d * L_SEQ + m) = vv;
            }
        }
    }
}

// ---------------------------------------------------------------------------
// gemm_out: same 64Mx128N BK=64 double-buffered template. Grid 512 = 2/CU.
// ---------------------------------------------------------------------------
__global__ __launch_bounds__(256, 3) void gemm_out(const bf16* __restrict__ A,
                                                   const bf16* __restrict__ Bt,
                                                   float* __restrict__ C) {
    constexpr int KDIM = D_MODEL;
    __shared__ __align__(16) bf16 As[2][64 * 64];
    __shared__ __align__(16) bf16 Bs[2][128 * 64];
    const int tid = threadIdx.x;
    const int wid = tid >> 6, lane = tid & 63;
    const int quad = lane >> 4, l15 = lane & 15;
    const int wm = wid & 1, wn = wid >> 1;
    const long m0 = (long)blockIdx.y * 64, n0 = (long)blockIdx.x * 128;

    f32x4 acc[2][4];
#pragma unroll
    for (int i = 0; i < 2; ++i)
#pragma unroll
        for (int j = 0; j < 4; ++j) acc[i][j] = (f32x4){0.f, 0.f, 0.f, 0.f};

    const int srow8 = lane >> 3;
    const int schunk = lane & 7;

    auto stage = [&](int k0, int buf) {
#pragma unroll
        for (int ii = 0; ii < 2; ++ii) {
            const int rowb = wid * 16 + ii * 8;
            const int row = rowb + srow8;
            const int gcol = (schunk ^ (row & 7)) * 8;
            GLD16(A + (m0 + row) * KDIM + k0 + gcol, &As[buf][rowb * 64]);
        }
#pragma unroll
        for (int ii = 0; ii < 4; ++ii) {
            const int rowb = wid * 32 + ii * 8;
            const int row = rowb + srow8;
            const int gcol = (schunk ^ (row & 7)) * 8;
            GLD16(Bt + (n0 + row) * KDIM + k0 + gcol, &Bs[buf][rowb * 64]);
        }
    };
    stage(0, 0);

    for (int k0 = 0; k0 < KDIM; k0 += 64) {
        __syncthreads();
        if (k0 + 64 < KDIM) stage(k0 + 64, ((k0 >> 6) + 1) & 1);
        const int buf = (k0 >> 6) & 1;
#pragma unroll
        for (int ks = 0; ks < 2; ++ks) {
            const int pos = ((ks * 4 + quad) ^ (l15 & 7)) * 8;
            bf16x8 af[2], bfr[4];
#pragma unroll
            for (int i = 0; i < 2; ++i)
                af[i] = *(const bf16x8*)&As[buf][(wm * 32 + i * 16 + l15) * 64 + pos];
#pragma unroll
            for (int j = 0; j < 4; ++j)
                bfr[j] = *(const bf16x8*)&Bs[buf][(j * 32 + wn * 16 + l15) * 64 + pos];
#pragma unroll
            for (int i = 0; i < 2; ++i)
#pragma unroll
                for (int j = 0; j < 4; ++j)
                    acc[i][j] = __builtin_amdgcn_mfma_f32_16x16x32_bf16(af[i], bfr[j], acc[i][j], 0, 0, 0);
        }
    }

#pragma unroll
    for (int i = 0; i < 2; ++i)
#pragma unroll
        for (int j = 0; j < 4; ++j) {
            const long row = m0 + wm * 32 + i * 16 + quad * 4;
            const long col = n0 + j * 32 + wn * 16 + l15;
#pragma unroll
            for (int r = 0; r < 4; ++r)
                C[(row + r) * (long)D_MODEL + col] = acc[i][j][r];
        }
}

// ---------------------------------------------------------------------------
// GQA attention half-job kernel. Round-1 job structure (512 blocks, 256 thr,
// 4 waves, 64-wide k-tiles, same staging / ktile interleave / 64KB LDS —
// 16MB fetch proven). NEW wave decomposition: wave = (wk key-half, wq
// q-half). Each wave reads only ITS 32 keys of K (8 b128) and ITS 32 key
// cols of V^T (16 b64): block-iter LDS read = 64KB vs r1's 128KB (r3's
// 256KB). Rationale: SQ_LDS_BANK_CONFLICT tracked total reads across
// r1/r2/r3 exactly (wide-read serialization rounds, not fixable swizzle
// conflicts) -> LDS pipe cost is pure volume; occupancy gains that also
// multiply volume were a wash (r3). Cost: wk=0/1 hold duplicate O accs for
// the same q-rows -> one end-of-job LDS exchange (64KB smem, dead after
// last tile; lane-linear f32 writes, conflict-free) + wk-split lpart.
// VGPR: oaccT 128 + qb 64 resident; launch_bounds(256,2) caps at 256.
// ---------------------------------------------------------------------------
__global__ __launch_bounds__(256, 2) void attn_p(const bf16* __restrict__ Qb,
                                                 const bf16* __restrict__ Kb,
                                                 const bf16* __restrict__ Vtb,
                                                 bf16* __restrict__ Opart,
                                                 float* __restrict__ lpart) {
    __shared__ __align__(1024) char smem[65536];

    const int bid = blockIdx.x;
    int t, hq, half;
    if (bid < 256) { t = bid >> 5; hq = (bid & 31) >> 1; half = bid & 1; }
    else { int b2 = bid - 256; t = 8 + (b2 >> 5); hq = (b2 & 31) >> 1; half = b2 & 1; }
    const int h = hq >> 2;
    const int q0 = t * 128;
    const int tid = threadIdx.x;
    const int w = tid >> 6;                  // wave 0..3
    const int wk = w & 1, wq = w >> 1;       // key-half, q-half
    const int lane = tid & 63;
    const int quad = lane >> 4, l15 = lane & 15;

    const bf16* Qg = Qb + (long)hq * L_SEQ * HD;
    const bf16* Kg = Kb + (long)h * L_SEQ * HD;
    const bf16* Vg = Vtb + (long)h * HD * L_SEQ;

    // Q as register B-frags: this wave's 64 q rows (4 rf frags)
    bf16x8 qb[4][4];
#pragma unroll
    for (int rf = 0; rf < 4; ++rf)
#pragma unroll
        for (int kkd = 0; kkd < 4; ++kkd)
            qb[rf][kkd] = *(const bf16x8*)(Qg + (long)(q0 + wq * 64 + rf * 16 + l15) * HD
                                              + kkd * 32 + quad * 8);

    f32x4 oaccT[4][8];
#pragma unroll
    for (int rf = 0; rf < 4; ++rf)
#pragma unroll
        for (int j = 0; j < 8; ++j) oaccT[rf][j] = (f32x4){0.f, 0.f, 0.f, 0.f};
    float lacc[4] = {0.f, 0.f, 0.f, 0.f};

    // valid 64-wide k-tiles: [0, locnt) U [2t, 32); n always even
    const int locnt = (2 * t - 14 > 0) ? (2 * t - 14) : 0;
    const int n = locnt + 32 - 2 * t;
    const int cnt = n >> 1;                  // this half-job's tile count

    auto ktile = [&](int idx) {
        const int i = 2 * idx + half;
        return (i < locnt) ? i : (2 * t + (i - locnt));
    };

    auto stage = [&](int idx, int buf) {
        const int k0 = ktile(idx) * 64;
        bf16* Ksb  = (bf16*)(smem + buf * 32768);
        bf16* Vtsb = (bf16*)(smem + buf * 32768 + 16384);
#pragma unroll
        for (int ii = 0; ii < 4; ++ii) {     // K tile: 64 keys x 128 d
            int rowb = w * 16 + ii * 4;
            int row = rowb + quad;
            GLD16(Kg + (long)(k0 + row) * HD + ((l15 ^ (row & 7)) * 8), &Ksb[rowb * 128]);
        }
#pragma unroll
        for (int ii = 0; ii < 4; ++ii) {     // V^T tile: 128 d x 64 keys
            int rowb = w * 32 + ii * 8;
            int row = rowb + (lane >> 3);
            GLD16(Vg + (long)row * L_SEQ + k0 + (((lane & 7) ^ (row & 7)) * 8), &Vtsb[rowb * 64]);
        }
    };

    stage(0, 0);

    for (int it = 0; it < cnt; ++it) {
        __syncthreads();                     // drains stage(it); prev reads done
        if (it + 1 < cnt) stage(it + 1, (it + 1) & 1);

        const int kt = ktile(it);
        const int k0 = kt * 64;
        const bf16* Ks  = (const bf16*)(smem + (it & 1) * 32768);
        const bf16* Vts = (const bf16*)(smem + (it & 1) * 32768 + 16384);

        // K frags for THIS wave's 32 keys only (8 ds_read_b128)
        bf16x8 ka[2][4];
#pragma unroll
        for (int kb = 0; kb < 2; ++kb)
#pragma unroll
            for (int kkd = 0; kkd < 4; ++kkd)
                ka[kb][kkd] = *(const bf16x8*)&Ks[(wk * 32 + kb * 16 + l15) * 128 +
                                                  (((kkd * 4 + quad) ^ (l15 & 7)) * 8)];

        // S^T = K Q^T : per wave 32 keys x 64 q
        f32x4 sacc[4][2];
        __builtin_amdgcn_s_setprio(1);
#pragma unroll
        for (int rf = 0; rf < 4; ++rf)
#pragma unroll
            for (int kb = 0; kb < 2; ++kb) {
                f32x4 acc = (f32x4){0.f, 0.f, 0.f, 0.f};
#pragma unroll
                for (int kkd = 0; kkd < 4; ++kkd)
                    acc = __builtin_amdgcn_mfma_f32_16x16x32_bf16(ka[kb][kkd], qb[rf][kkd], acc, 0, 0, 0);
                sacc[rf][kb] = acc;
            }
        __builtin_amdgcn_s_setprio(0);

        // mask boundary tiles + exp2 + pack P^T B-frags + l accumulate
        const bool bnd = (kt == 2 * t) || (kt == 2 * t + 1) ||
                         (kt == 2 * t - 15) || (kt == 2 * t - 16);
        s16x4 pb[4][2];
#pragma unroll
        for (int rf = 0; rf < 4; ++rf) {
            const int qq = q0 + wq * 64 + rf * 16 + l15;
#pragma unroll
            for (int kb = 0; kb < 2; ++kb) {
#pragma unroll
                for (int r = 0; r < 4; ++r) {
                    float v = sacc[rf][kb][r];
                    if (bnd) {
                        const int kk = k0 + wk * 32 + kb * 16 + quad * 4 + r;
                        if (!((kk > qq) || (kk <= qq - 1024))) v = -1e30f;
                    }
                    const float p = exp2f(v);
                    lacc[rf] += p;
                    bf16 hp = (bf16)p;
                    pb[rf][kb][r] = __builtin_bit_cast(short, hp);
                }
            }
        }

        // O^T += V^T P^T over THIS wave's 32 keys (16 ds_read_b64)
        __builtin_amdgcn_s_setprio(1);
#pragma unroll
        for (int j = 0; j < 8; ++j) {
            const int drow = j * 16 + l15;
#pragma unroll
            for (int kq = 0; kq < 2; ++kq) {
                const int pc = (wk * 4 + kq * 2 + (quad >> 1)) ^ (l15 & 7);
                s16x4 va = *(const s16x4*)((const char*)&Vts[drow * 64] + pc * 16 + (quad & 1) * 8);
#pragma unroll
                for (int rf = 0; rf < 4; ++rf)
                    oaccT[rf][j] = __builtin_amdgcn_mfma_f32_16x16x16bf16_1k(
                        va, pb[rf][kq], oaccT[rf][j], 0, 0, 0);
            }
        }
        __builtin_amdgcn_s_setprio(0);
    }

    // reduce l across quads (keys span quads)
#pragma unroll
    for (int rf = 0; rf < 4; ++rf) {
        lacc[rf] += __shfl_xor(lacc[rf], 16, 64);
        lacc[rf] += __shfl_xor(lacc[rf], 32, 64);
    }

    // cross-wk O reduction through smem (K/V staging dead now).
    // Partner waves (wk=0/1, same wq) have IDENTICAL lane layouts -> pure
    // lane-linear exchange, conflict-free b128s. 2 writer waves x 32KB = 64KB.
    __syncthreads();
    if (wk) {
        float* xch = (float*)smem;
#pragma unroll
        for (int rf = 0; rf < 4; ++rf)
#pragma unroll
            for (int j = 0; j < 8; ++j)
                *(f32x4*)(xch + ((wq * 32 + rf * 8 + j) * 64 + lane) * 4) = oaccT[rf][j];
    }
    __syncthreads();

    bf16* Od = Opart + (long)bid * 16384;
    if (!wk) {
        const float* xch = (const float*)smem;
#pragma unroll
        for (int rf = 0; rf < 4; ++rf) {
            const int ql = wq * 64 + rf * 16 + l15;
#pragma unroll
            for (int j = 0; j < 8; ++j) {
                f32x4 o = *(const f32x4*)(xch + ((wq * 32 + rf * 8 + j) * 64 + lane) * 4);
                o += oaccT[rf][j];
                bf16x4v ov;
#pragma unroll
                for (int r = 0; r < 4; ++r) ov[r] = (bf16)o[r];
                *(bf16x4v*)(Od + ql * 128 + j * 16 + quad * 4) = ov;
            }
        }
    }
    // l partials: both wk halves write their own slot; combine sums 4.
    if (quad == 0) {
#pragma unroll
        for (int rf = 0; rf < 4; ++rf)
            lpart[bid * 256 + wk * 128 + wq * 64 + rf * 16 + l15] = lacc[rf];
    }
}

// ---------------------------------------------------------------------------
// combine: attnb = (O0+O1) / (sum of 4 l-partials + exp2(sink*log2e))
// ---------------------------------------------------------------------------
__global__ __launch_bounds__(256) void attn_combine(const bf16* __restrict__ Opart,
                                                    const float* __restrict__ lpart,
                                                    const float* __restrict__ sink,
                                                    bf16* __restrict__ attnb) {
    const int job = blockIdx.x >> 3, sub = blockIdx.x & 7;
    const int t = job >> 4, hq = job & 15;
    const int bid0 = (t < 8) ? (t * 32 + hq * 2) : (256 + (t - 8) * 32 + hq * 2);
    const int bid1 = bid0 + 1;
    const int e = sub * 2048 + threadIdx.x * 8;
    const int q = e >> 7, d0 = e & 127;
    bf16x8 o0 = *(const bf16x8*)(Opart + (long)bid0 * 16384 + q * 128 + d0);
    bf16x8 o1 = *(const bf16x8*)(Opart + (long)bid1 * 16384 + q * 128 + d0);
    const float l = lpart[bid0 * 256 + q] + lpart[bid0 * 256 + 128 + q] +
                    lpart[bid1 * 256 + q] + lpart[bid1 * 256 + 128 + q] +
                    exp2f(sink[hq] * LOG2E);
    const float inv = 1.0f / l;
    bf16x8 ov;
#pragma unroll
    for (int r = 0; r < 8; ++r)
        ov[r] = (bf16)(((float)o0[r] + (float)o1[r]) * inv);
    *(bf16x8*)(attnb + (long)(t * 128 + q) * D_MODEL + hq * 128 + d0) = ov;
}

// ---------------------------------------------------------------------------
extern "C" void kernel_launch(void* const* d_in, const int* in_sizes, int n_in,
                              void* d_out, int out_size, void* d_ws, size_t ws_size,
                              hipStream_t stream) {
    (void)in_sizes; (void)n_in; (void)out_size; (void)ws_size;
    const float* x    = (const float*)d_in[0];
    const float* Wqkv = (const float*)d_in[1];
    const float* Wo   = (const float*)d_in[2];
    const float* s    = (const float*)d_in[3];
    float* out = (float*)d_out;

    // persistent layout (48 MB): [xb 8M][wqkvT 12.6M][Qb 8M][Kb 2M][Vtb 2M]
    //                            [woT 8M][attnb 8M]
    // Opart (16.8M bf16) + lpart (0.5M) alias [xb..wqkvT] (dead during attn).
    char* ws = (char*)d_ws;
    bf16* xb    = (bf16*)ws;
    bf16* wqkvT = (bf16*)(ws + 8388608);
    bf16* Qb    = (bf16*)(ws + 20971520);
    bf16* Kb    = (bf16*)(ws + 29360128);
    bf16* Vtb   = (bf16*)(ws + 31457280);
    bf16* woT   = (bf16*)(ws + 33554432);
    bf16* attnb = (bf16*)(ws + 41943040);
    bf16* Opart = (bf16*)ws;                  // 512 x 128 x 128 bf16
    float* lpart = (float*)(ws + 16777216);   // 512 x 2 x 128 f32

    prep<<<14336, 256, 0, stream>>>(x, Wqkv, Wo, xb, wqkvT, woT);

    gemm_qkv<<<dim3(QKV_N / 128, L_SEQ / 64), 256, 0, stream>>>(
        xb, wqkvT, Qb, Kb, Vtb);

    attn_p<<<512, 256, 0, stream>>>(Qb, Kb, Vtb, Opart, lpart);

    attn_combine<<<2048, 256, 0, stream>>>(Opart, lpart, s, attnb);

    gemm_out<<<dim3(D_MODEL / 128, L_SEQ / 64), 256, 0, stream>>>(
        attnb, woT, out);
}

// Round 5
// 220.721 us; speedup vs baseline: 1.2197x; 1.2197x over previous
//
#include <hip/hip_runtime.h>
#include <hip/hip_bf16.h>
#include <math.h>

typedef __bf16 bf16;
typedef __bf16 bf16x8 __attribute__((ext_vector_type(8)));
typedef __bf16 bf16x4v __attribute__((ext_vector_type(4)));
typedef short s16x4 __attribute__((ext_vector_type(4)));
typedef float f32x4 __attribute__((ext_vector_type(4)));

#define GLD16(gp, lp) __builtin_amdgcn_global_load_lds( \
    (__attribute__((address_space(1))) void*)(void*)(gp), \
    (__attribute__((address_space(3))) void*)(lp), 16, 0, 0)

#define L_SEQ 2048
#define D_MODEL 2048
#define QKV_N 3072
#define HD 128
#define QSCALE 0.1275310242959836f               // (1/sqrt(128)) * log2(e)
#define LOG2E 1.4426950408889634f

// ---------------------------------------------------------------------------
// prep: fused  (a) x f32->bf16 cast  (b) Wqkv^T cast  (c) Wo^T cast
// ---------------------------------------------------------------------------
__global__ __launch_bounds__(256) void prep(const float* __restrict__ x,
                                            const float* __restrict__ Wqkv,
                                            const float* __restrict__ Wo,
                                            bf16* __restrict__ xb,
                                            bf16* __restrict__ wqkvT,
                                            bf16* __restrict__ woT) {
    __shared__ float tile[32][33];
    int bid = blockIdx.x;
    if (bid < 4096) {                       // cast x (4M elems, 4/thread)
        int idx = (bid * 256 + threadIdx.x) * 4;
        float4 f = *(const float4*)(x + idx);
        bf16x4v o;
        o.x = (bf16)f.x; o.y = (bf16)f.y; o.z = (bf16)f.z; o.w = (bf16)f.w;
        *(bf16x4v*)(xb + idx) = o;
        return;
    }
    bid -= 4096;
    const float* src; bf16* dst; long ld_s, ld_d; int bx, by;
    if (bid < 6144) { bx = bid % 96; by = bid / 96; src = Wqkv; dst = wqkvT; ld_s = QKV_N; ld_d = D_MODEL; }
    else { bid -= 6144; bx = bid & 63; by = bid >> 6; src = Wo; dst = woT; ld_s = D_MODEL; ld_d = D_MODEL; }
    const int tx = threadIdx.x & 31, ty = threadIdx.x >> 5;
    const long c = bx * 32 + tx, r0 = by * 32;
#pragma unroll
    for (int i = 0; i < 4; ++i)
        tile[ty + i * 8][tx] = src[(r0 + ty + i * 8) * ld_s + c];
    __syncthreads();
    const long c0 = bx * 32;
#pragma unroll
    for (int i = 0; i < 4; ++i)
        dst[(c0 + ty + i * 8) * ld_d + r0 + tx] = (bf16)tile[tx][ty + i * 8];
}

// ---------------------------------------------------------------------------
// gemm_qkv: 64Mx128N block, 4 waves (2Mx2N), wave tile 32x64, BK=64 dbuf.
// Grid 24x32 = 768 blocks @ 48KB LDS = 3 blocks/CU. (r1 version: proven
// >=10us better than the r0 128x128 variant — left the top-5.)
// ---------------------------------------------------------------------------
__global__ __launch_bounds__(256, 3) void gemm_qkv(const bf16* __restrict__ A,
                                                   const bf16* __restrict__ Bt,
                                                   bf16* __restrict__ Qb,
                                                   bf16* __restrict__ Kb,
                                                   bf16* __restrict__ Vtb) {
    constexpr int KDIM = D_MODEL;
    __shared__ __align__(16) bf16 As[2][64 * 64];
    __shared__ __align__(16) bf16 Bs[2][128 * 64];
    const int tid = threadIdx.x;
    const int wid = tid >> 6, lane = tid & 63;
    const int quad = lane >> 4, l15 = lane & 15;
    const int wm = wid & 1, wn = wid >> 1;
    const int head = blockIdx.x;
    const long m0 = (long)blockIdx.y * 64, n0 = (long)head * 128;

    f32x4 acc[2][4];
#pragma unroll
    for (int i = 0; i < 2; ++i)
#pragma unroll
        for (int j = 0; j < 4; ++j) acc[i][j] = (f32x4){0.f, 0.f, 0.f, 0.f};

    const int srow8 = lane >> 3;             // row within 8-row group
    const int schunk = lane & 7;             // LDS chunk position

    auto stage = [&](int k0, int buf) {
#pragma unroll
        for (int ii = 0; ii < 2; ++ii) {     // A tile: 64 rows
            const int rowb = wid * 16 + ii * 8;
            const int row = rowb + srow8;
            const int gcol = (schunk ^ (row & 7)) * 8;
            GLD16(A + (m0 + row) * KDIM + k0 + gcol, &As[buf][rowb * 64]);
        }
#pragma unroll
        for (int ii = 0; ii < 4; ++ii) {     // B tile: 128 rows
            const int rowb = wid * 32 + ii * 8;
            const int row = rowb + srow8;
            const int gcol = (schunk ^ (row & 7)) * 8;
            GLD16(Bt + (n0 + row) * KDIM + k0 + gcol, &Bs[buf][rowb * 64]);
        }
    };
    stage(0, 0);

    for (int k0 = 0; k0 < KDIM; k0 += 64) {
        __syncthreads();
        if (k0 + 64 < KDIM) stage(k0 + 64, ((k0 >> 6) + 1) & 1);
        const int buf = (k0 >> 6) & 1;
#pragma unroll
        for (int ks = 0; ks < 2; ++ks) {
            const int pos = ((ks * 4 + quad) ^ (l15 & 7)) * 8;
            bf16x8 af[2], bfr[4];
#pragma unroll
            for (int i = 0; i < 2; ++i)
                af[i] = *(const bf16x8*)&As[buf][(wm * 32 + i * 16 + l15) * 64 + pos];
#pragma unroll
            for (int j = 0; j < 4; ++j)
                bfr[j] = *(const bf16x8*)&Bs[buf][(j * 32 + wn * 16 + l15) * 64 + pos];
#pragma unroll
            for (int i = 0; i < 2; ++i)
#pragma unroll
                for (int j = 0; j < 4; ++j)
                    acc[i][j] = __builtin_amdgcn_mfma_f32_16x16x32_bf16(af[i], bfr[j], acc[i][j], 0, 0, 0);
        }
    }

    if (head < 20) {                                   // Q or K head: RoPE
        const float sc = head < 16 ? QSCALE : 1.0f;
        bf16* dst = head < 16 ? Qb + (long)head * L_SEQ * HD
                              : Kb + (long)(head - 16) * L_SEQ * HD;
        const int d0 = wn * 16 + l15;                  // rotate pair (j=0, j=2)
        const float freq = exp2f((float)d0 * (-10.0f / 31.0f));
        const int d1 = 32 + wn * 16 + l15;             // identity pair (j=1, j=3)
#pragma unroll
        for (int i = 0; i < 2; ++i)
#pragma unroll
            for (int r = 0; r < 4; ++r) {
                const long row = m0 + wm * 32 + i * 16 + quad * 4 + r;
                float sn, cs;
                sincosf((float)row * freq, &sn, &cs);
                const float x1 = acc[i][0][r], x2 = acc[i][2][r];
                bf16* p = dst + row * HD;
                p[d0]      = (bf16)((x1 * cs + x2 * sn) * sc);
                p[d0 + 64] = (bf16)((x2 * cs - x1 * sn) * sc);
                p[d1]      = (bf16)(acc[i][1][r] * sc);
                p[d1 + 64] = (bf16)(acc[i][3][r] * sc);
            }
    } else {                                           // V head: write V^T[d][l]
        bf16* dst = Vtb + (long)(head - 20) * HD * L_SEQ;
#pragma unroll
        for (int i = 0; i < 2; ++i) {
            const long m = m0 + wm * 32 + i * 16 + quad * 4;
#pragma unroll
            for (int j = 0; j < 4; ++j) {
                const int d = j * 32 + wn * 16 + l15;
                bf16x4v vv;
#pragma unroll
                for (int r = 0; r < 4; ++r) vv[r] = (bf16)acc[i][j][r];
                *(bf16x4v*)(dst + (long)d * L_SEQ + m) = vv;
            }
        }
    }
}

// ---------------------------------------------------------------------------
// gemm_out: REVERTED to the r0 "R8 known-good" version. The r1 template
// transplant (48KB dbuf BK=64) regressed ~10us: deduced from r0->r1 totals
// (gemm_qkv left top-5 with a >=10us win yet total moved 218.7->218.4 with
// all other kernels byte-identical). 12KB LDS here -> high block residency.
// ---------------------------------------------------------------------------
__global__ __launch_bounds__(256) void gemm_out(const bf16* __restrict__ A,
                                                const bf16* __restrict__ Bt,
                                                float* __restrict__ C) {
    constexpr int KDIM = D_MODEL;
    __shared__ __align__(16) bf16 As[64 * 32];
    __shared__ __align__(16) bf16 Bs[128 * 32];
    const int tid = threadIdx.x;
    const int wid = tid >> 6, lane = tid & 63;
    const int quad = lane >> 4, l15 = lane & 15;
    const long m0 = (long)blockIdx.y * 64, n0 = (long)blockIdx.x * 128;
    const int srowA = wid * 16 + (lane >> 2);
    const int srowB = wid * 32 + (lane >> 2);
    const int scol = ((lane & 3) ^ ((lane >> 3) & 3)) * 8;
    f32x4 acc[8];
#pragma unroll
    for (int j = 0; j < 8; ++j) acc[j] = (f32x4){0.f, 0.f, 0.f, 0.f};
    const bf16* Ap  = A  + (m0 + srowA) * KDIM + scol;
    const bf16* Bp  = Bt + (n0 + srowB) * KDIM + scol;
    const bf16* Bp2 = Bp + (long)16 * KDIM;
    bf16* lA  = &As[(wid * 16) * 32];
    bf16* lB  = &Bs[(wid * 32) * 32];
    bf16* lB2 = &Bs[(wid * 32 + 16) * 32];
    const int rsw = ((l15 >> 1) & 3);
    for (int k0 = 0; k0 < KDIM; k0 += 32) {
        GLD16(Ap + k0, lA);
        GLD16(Bp + k0, lB);
        GLD16(Bp2 + k0, lB2);
        __syncthreads();
        bf16x8 af = *(const bf16x8*)&As[(wid * 16 + l15) * 32 + (quad ^ rsw) * 8];
        bf16x8 bfr[8];
#pragma unroll
        for (int j = 0; j < 8; ++j)
            bfr[j] = *(const bf16x8*)&Bs[(j * 16 + l15) * 32 + (quad ^ rsw) * 8];
#pragma unroll
        for (int j = 0; j < 8; ++j)
            acc[j] = __builtin_amdgcn_mfma_f32_16x16x32_bf16(af, bfr[j], acc[j], 0, 0, 0);
        __syncthreads();
    }
#pragma unroll
    for (int j = 0; j < 8; ++j) {
        const long m = m0 + wid * 16 + quad * 4;
        const long n = n0 + j * 16 + l15;
#pragma unroll
        for (int r = 0; r < 4; ++r)
            C[(m + r) * (long)D_MODEL + n] = acc[j][r];
    }
}

// ---------------------------------------------------------------------------
// GQA attention half-job kernel — REVERTED to the r1 structure (proven 49us,
// 16.4MB fetch, VGPR 108; three rewrites r2/r3/r4 all lost to it: r2 traffic
// explosion 302MB, r3 2x LDS-read volume, r4 VGPR spills at 128-cap).
// ONE delta vs r1: s_setprio(1) around the two MFMA clusters (T5, measured
// +4-7% on attn, m191).
// ---------------------------------------------------------------------------
__global__ __launch_bounds__(256, 2) void attn_p(const bf16* __restrict__ Qb,
                                                 const bf16* __restrict__ Kb,
                                                 const bf16* __restrict__ Vtb,
                                                 bf16* __restrict__ Opart,
                                                 float* __restrict__ lpart) {
    __shared__ __align__(1024) char smem[65536];

    const int bid = blockIdx.x;
    int t, hq, half;
    if (bid < 256) { t = bid >> 5; hq = (bid & 31) >> 1; half = bid & 1; }
    else { int b2 = bid - 256; t = 8 + (b2 >> 5); hq = (b2 & 31) >> 1; half = b2 & 1; }
    const int h = hq >> 2;
    const int q0 = t * 128;
    const int tid = threadIdx.x;
    const int w = tid >> 6;                  // wave 0..3, owns q rows w*32..+31
    const int lane = tid & 63;
    const int quad = lane >> 4, l15 = lane & 15;

    const bf16* Qg = Qb + (long)hq * L_SEQ * HD;
    const bf16* Kg = Kb + (long)h * L_SEQ * HD;
    const bf16* Vg = Vtb + (long)h * HD * L_SEQ;

    // Q as register B-frags
    bf16x8 qb[2][4];
#pragma unroll
    for (int rf = 0; rf < 2; ++rf)
#pragma unroll
        for (int kkd = 0; kkd < 4; ++kkd)
            qb[rf][kkd] = *(const bf16x8*)(Qg + (long)(q0 + w * 32 + rf * 16 + l15) * HD
                                              + kkd * 32 + quad * 8);

    f32x4 oaccT[2][8];
#pragma unroll
    for (int rf = 0; rf < 2; ++rf)
#pragma unroll
        for (int j = 0; j < 8; ++j) oaccT[rf][j] = (f32x4){0.f, 0.f, 0.f, 0.f};
    float lacc[2] = {0.f, 0.f};

    // valid 64-wide k-tiles: [0, locnt) U [2t, 32); n always even
    const int locnt = (2 * t - 14 > 0) ? (2 * t - 14) : 0;
    const int n = locnt + 32 - 2 * t;
    const int cnt = n >> 1;                  // this half-job's tile count

    auto ktile = [&](int idx) {
        const int i = 2 * idx + half;
        return (i < locnt) ? i : (2 * t + (i - locnt));
    };

    auto stage = [&](int idx, int buf) {
        const int k0 = ktile(idx) * 64;
        bf16* Ksb  = (bf16*)(smem + buf * 32768);
        bf16* Vtsb = (bf16*)(smem + buf * 32768 + 16384);
#pragma unroll
        for (int ii = 0; ii < 4; ++ii) {     // K tile: 64 keys x 128 d
            int rowb = w * 16 + ii * 4;
            int row = rowb + quad;
            GLD16(Kg + (long)(k0 + row) * HD + ((l15 ^ (row & 7)) * 8), &Ksb[rowb * 128]);
        }
#pragma unroll
        for (int ii = 0; ii < 4; ++ii) {     // V^T tile: 128 d x 64 keys
            int rowb = w * 32 + ii * 8;
            int row = rowb + (lane >> 3);
            GLD16(Vg + (long)row * L_SEQ + k0 + (((lane & 7) ^ (row & 7)) * 8), &Vtsb[rowb * 64]);
        }
    };

    stage(0, 0);

    for (int it = 0; it < cnt; ++it) {
        __syncthreads();                     // drains stage(it); prev reads done
        if (it + 1 < cnt) stage(it + 1, (it + 1) & 1);

        const int kt = ktile(it);
        const int k0 = kt * 64;
        const bf16* Ks  = (const bf16*)(smem + (it & 1) * 32768);
        const bf16* Vts = (const bf16*)(smem + (it & 1) * 32768 + 16384);

        // S^T = K Q^T : per wave 64 keys x 32 q
        f32x4 sacc[2][4];
        __builtin_amdgcn_s_setprio(1);
#pragma unroll
        for (int kb = 0; kb < 4; ++kb) {
            bf16x8 ka[4];
#pragma unroll
            for (int kkd = 0; kkd < 4; ++kkd)
                ka[kkd] = *(const bf16x8*)&Ks[(kb * 16 + l15) * 128 +
                                              (((kkd * 4 + quad) ^ (l15 & 7)) * 8)];
#pragma unroll
            for (int rf = 0; rf < 2; ++rf) {
                f32x4 acc = (f32x4){0.f, 0.f, 0.f, 0.f};
#pragma unroll
                for (int kkd = 0; kkd < 4; ++kkd)
                    acc = __builtin_amdgcn_mfma_f32_16x16x32_bf16(ka[kkd], qb[rf][kkd], acc, 0, 0, 0);
                sacc[rf][kb] = acc;
            }
        }
        __builtin_amdgcn_s_setprio(0);

        // mask boundary tiles + exp2 + pack P^T B-frags + l accumulate
        const bool bnd = (kt == 2 * t) || (kt == 2 * t + 1) ||
                         (kt == 2 * t - 15) || (kt == 2 * t - 16);
        s16x4 pb[2][4];
#pragma unroll
        for (int rf = 0; rf < 2; ++rf) {
            const int qq = q0 + w * 32 + rf * 16 + l15;
#pragma unroll
            for (int kb = 0; kb < 4; ++kb) {
#pragma unroll
                for (int r = 0; r < 4; ++r) {
                    float v = sacc[rf][kb][r];
                    if (bnd) {
                        const int kk = k0 + kb * 16 + quad * 4 + r;
                        if (!((kk > qq) || (kk <= qq - 1024))) v = -1e30f;
                    }
                    const float p = exp2f(v);
                    lacc[rf] += p;
                    bf16 hp = (bf16)p;
                    pb[rf][kb][r] = __builtin_bit_cast(short, hp);
                }
            }
        }

        // O^T += V^T P^T : 16x16x16 MFMA, A from LDS, B from registers
        __builtin_amdgcn_s_setprio(1);
#pragma unroll
        for (int j = 0; j < 8; ++j) {
            const int drow = j * 16 + l15;
#pragma unroll
            for (int kq = 0; kq < 4; ++kq) {
                const int pc = ((kq * 2 + (quad >> 1)) ^ (l15 & 7));
                s16x4 va = *(const s16x4*)((const char*)&Vts[drow * 64] + pc * 16 + (quad & 1) * 8);
#pragma unroll
                for (int rf = 0; rf < 2; ++rf)
                    oaccT[rf][j] = __builtin_amdgcn_mfma_f32_16x16x16bf16_1k(
                        va, pb[rf][kq], oaccT[rf][j], 0, 0, 0);
            }
        }
        __builtin_amdgcn_s_setprio(0);
    }

    // reduce l across quads (keys span quads)
#pragma unroll
    for (int rf = 0; rf < 2; ++rf) {
        lacc[rf] += __shfl_xor(lacc[rf], 16, 64);
        lacc[rf] += __shfl_xor(lacc[rf], 32, 64);
    }

    // write partials: Opart[bid][q 128][d 128] bf16, lpart[bid][q] f32
    bf16* Od = Opart + (long)bid * 16384;
#pragma unroll
    for (int rf = 0; rf < 2; ++rf) {
        const int ql = w * 32 + rf * 16 + l15;
#pragma unroll
        for (int j = 0; j < 8; ++j) {
            bf16x4v ov;
#pragma unroll
            for (int r = 0; r < 4; ++r) ov[r] = (bf16)oaccT[rf][j][r];
            *(bf16x4v*)(Od + ql * 128 + j * 16 + quad * 4) = ov;
        }
        if (quad == 0) lpart[bid * 128 + ql] = lacc[rf];
    }
}

// ---------------------------------------------------------------------------
// combine: attnb[q][hq*128+d] = (O0+O1) / (l0+l1+exp2(sink*log2e))
// ---------------------------------------------------------------------------
__global__ __launch_bounds__(256) void attn_combine(const bf16* __restrict__ Opart,
                                                    const float* __restrict__ lpart,
                                                    const float* __restrict__ sink,
                                                    bf16* __restrict__ attnb) {
    const int job = blockIdx.x >> 3, sub = blockIdx.x & 7;
    const int t = job >> 4, hq = job & 15;
    const int bid0 = (t < 8) ? (t * 32 + hq * 2) : (256 + (t - 8) * 32 + hq * 2);
    const int bid1 = bid0 + 1;
    const int e = sub * 2048 + threadIdx.x * 8;
    const int q = e >> 7, d0 = e & 127;
    bf16x8 o0 = *(const bf16x8*)(Opart + (long)bid0 * 16384 + q * 128 + d0);
    bf16x8 o1 = *(const bf16x8*)(Opart + (long)bid1 * 16384 + q * 128 + d0);
    const float l = lpart[bid0 * 128 + q] + lpart[bid1 * 128 + q] +
                    exp2f(sink[hq] * LOG2E);
    const float inv = 1.0f / l;
    bf16x8 ov;
#pragma unroll
    for (int r = 0; r < 8; ++r)
        ov[r] = (bf16)(((float)o0[r] + (float)o1[r]) * inv);
    *(bf16x8*)(attnb + (long)(t * 128 + q) * D_MODEL + hq * 128 + d0) = ov;
}

// ---------------------------------------------------------------------------
extern "C" void kernel_launch(void* const* d_in, const int* in_sizes, int n_in,
                              void* d_out, int out_size, void* d_ws, size_t ws_size,
                              hipStream_t stream) {
    (void)in_sizes; (void)n_in; (void)out_size; (void)ws_size;
    const float* x    = (const float*)d_in[0];
    const float* Wqkv = (const float*)d_in[1];
    const float* Wo   = (const float*)d_in[2];
    const float* s    = (const float*)d_in[3];
    float* out = (float*)d_out;

    // persistent layout (48 MB): [xb 8M][wqkvT 12.6M][Qb 8M][Kb 2M][Vtb 2M]
    //                            [woT 8M][attnb 8M]
    // Opart (16.8M bf16) + lpart (0.25M) alias [xb..wqkvT] (dead during attn).
    char* ws = (char*)d_ws;
    bf16* xb    = (bf16*)ws;
    bf16* wqkvT = (bf16*)(ws + 8388608);
    bf16* Qb    = (bf16*)(ws + 20971520);
    bf16* Kb    = (bf16*)(ws + 29360128);
    bf16* Vtb   = (bf16*)(ws + 31457280);
    bf16* woT   = (bf16*)(ws + 33554432);
    bf16* attnb = (bf16*)(ws + 41943040);
    bf16* Opart = (bf16*)ws;                  // 512 x 128 x 128 bf16
    float* lpart = (float*)(ws + 16777216);   // 512 x 128 f32

    prep<<<14336, 256, 0, stream>>>(x, Wqkv, Wo, xb, wqkvT, woT);

    gemm_qkv<<<dim3(QKV_N / 128, L_SEQ / 64), 256, 0, stream>>>(
        xb, wqkvT, Qb, Kb, Vtb);

    attn_p<<<512, 256, 0, stream>>>(Qb, Kb, Vtb, Opart, lpart);

    attn_combine<<<2048, 256, 0, stream>>>(Opart, lpart, s, attnb);

    gemm_out<<<dim3(D_MODEL / 128, L_SEQ / 64), 256, 0, stream>>>(
        attnb, woT, out);
}

// Round 7
// 215.036 us; speedup vs baseline: 1.2520x; 1.0264x over previous
//
#include <hip/hip_runtime.h>
#include <hip/hip_bf16.h>
#include <math.h>

typedef __bf16 bf16;
typedef __bf16 bf16x8 __attribute__((ext_vector_type(8)));
typedef __bf16 bf16x4v __attribute__((ext_vector_type(4)));
typedef short s16x4 __attribute__((ext_vector_type(4)));
typedef float f32x4 __attribute__((ext_vector_type(4)));

#define GLD16(gp, lp) __builtin_amdgcn_global_load_lds( \
    (__attribute__((address_space(1))) void*)(void*)(gp), \
    (__attribute__((address_space(3))) void*)(lp), 16, 0, 0)

#define L_SEQ 2048
#define D_MODEL 2048
#define QKV_N 3072
#define HD 128
#define QSCALE 0.1275310242959836f               // (1/sqrt(128)) * log2(e)
#define LOG2E 1.4426950408889634f

// ---------------------------------------------------------------------------
// prep: fused  (a) x f32->bf16 cast  (b) Wqkv^T cast  (c) Wo^T cast
// ---------------------------------------------------------------------------
__global__ __launch_bounds__(256) void prep(const float* __restrict__ x,
                                            const float* __restrict__ Wqkv,
                                            const float* __restrict__ Wo,
                                            bf16* __restrict__ xb,
                                            bf16* __restrict__ wqkvT,
                                            bf16* __restrict__ woT) {
    __shared__ float tile[32][33];
    int bid = blockIdx.x;
    if (bid < 4096) {                       // cast x (4M elems, 4/thread)
        int idx = (bid * 256 + threadIdx.x) * 4;
        float4 f = *(const float4*)(x + idx);
        bf16x4v o;
        o.x = (bf16)f.x; o.y = (bf16)f.y; o.z = (bf16)f.z; o.w = (bf16)f.w;
        *(bf16x4v*)(xb + idx) = o;
        return;
    }
    bid -= 4096;
    const float* src; bf16* dst; long ld_s, ld_d; int bx, by;
    if (bid < 6144) { bx = bid % 96; by = bid / 96; src = Wqkv; dst = wqkvT; ld_s = QKV_N; ld_d = D_MODEL; }
    else { bid -= 6144; bx = bid & 63; by = bid >> 6; src = Wo; dst = woT; ld_s = D_MODEL; ld_d = D_MODEL; }
    const int tx = threadIdx.x & 31, ty = threadIdx.x >> 5;
    const long c = bx * 32 + tx, r0 = by * 32;
#pragma unroll
    for (int i = 0; i < 4; ++i)
        tile[ty + i * 8][tx] = src[(r0 + ty + i * 8) * ld_s + c];
    __syncthreads();
    const long c0 = bx * 32;
#pragma unroll
    for (int i = 0; i < 4; ++i)
        dst[(c0 + ty + i * 8) * ld_d + r0 + tx] = (bf16)tile[tx][ty + i * 8];
}

// ---------------------------------------------------------------------------
// gemm_qkv: 64Mx128N block, 4 waves (2Mx2N), wave tile 32x64, BK=64 dbuf.
// Grid 24x32 = 768 blocks @ 48KB LDS = 3 blocks/CU. (r1 version, frozen.)
// ---------------------------------------------------------------------------
__global__ __launch_bounds__(256, 3) void gemm_qkv(const bf16* __restrict__ A,
                                                   const bf16* __restrict__ Bt,
                                                   bf16* __restrict__ Qb,
                                                   bf16* __restrict__ Kb,
                                                   bf16* __restrict__ Vtb) {
    constexpr int KDIM = D_MODEL;
    __shared__ __align__(16) bf16 As[2][64 * 64];
    __shared__ __align__(16) bf16 Bs[2][128 * 64];
    const int tid = threadIdx.x;
    const int wid = tid >> 6, lane = tid & 63;
    const int quad = lane >> 4, l15 = lane & 15;
    const int wm = wid & 1, wn = wid >> 1;
    const int head = blockIdx.x;
    const long m0 = (long)blockIdx.y * 64, n0 = (long)head * 128;

    f32x4 acc[2][4];
#pragma unroll
    for (int i = 0; i < 2; ++i)
#pragma unroll
        for (int j = 0; j < 4; ++j) acc[i][j] = (f32x4){0.f, 0.f, 0.f, 0.f};

    const int srow8 = lane >> 3;             // row within 8-row group
    const int schunk = lane & 7;             // LDS chunk position

    auto stage = [&](int k0, int buf) {
#pragma unroll
        for (int ii = 0; ii < 2; ++ii) {     // A tile: 64 rows
            const int rowb = wid * 16 + ii * 8;
            const int row = rowb + srow8;
            const int gcol = (schunk ^ (row & 7)) * 8;
            GLD16(A + (m0 + row) * KDIM + k0 + gcol, &As[buf][rowb * 64]);
        }
#pragma unroll
        for (int ii = 0; ii < 4; ++ii) {     // B tile: 128 rows
            const int rowb = wid * 32 + ii * 8;
            const int row = rowb + srow8;
            const int gcol = (schunk ^ (row & 7)) * 8;
            GLD16(Bt + (n0 + row) * KDIM + k0 + gcol, &Bs[buf][rowb * 64]);
        }
    };
    stage(0, 0);

    for (int k0 = 0; k0 < KDIM; k0 += 64) {
        __syncthreads();
        if (k0 + 64 < KDIM) stage(k0 + 64, ((k0 >> 6) + 1) & 1);
        const int buf = (k0 >> 6) & 1;
#pragma unroll
        for (int ks = 0; ks < 2; ++ks) {
            const int pos = ((ks * 4 + quad) ^ (l15 & 7)) * 8;
            bf16x8 af[2], bfr[4];
#pragma unroll
            for (int i = 0; i < 2; ++i)
                af[i] = *(const bf16x8*)&As[buf][(wm * 32 + i * 16 + l15) * 64 + pos];
#pragma unroll
            for (int j = 0; j < 4; ++j)
                bfr[j] = *(const bf16x8*)&Bs[buf][(j * 32 + wn * 16 + l15) * 64 + pos];
#pragma unroll
            for (int i = 0; i < 2; ++i)
#pragma unroll
                for (int j = 0; j < 4; ++j)
                    acc[i][j] = __builtin_amdgcn_mfma_f32_16x16x32_bf16(af[i], bfr[j], acc[i][j], 0, 0, 0);
        }
    }

    if (head < 20) {                                   // Q or K head: RoPE
        const float sc = head < 16 ? QSCALE : 1.0f;
        bf16* dst = head < 16 ? Qb + (long)head * L_SEQ * HD
                              : Kb + (long)(head - 16) * L_SEQ * HD;
        const int d0 = wn * 16 + l15;                  // rotate pair (j=0, j=2)
        const float freq = exp2f((float)d0 * (-10.0f / 31.0f));
        const int d1 = 32 + wn * 16 + l15;             // identity pair (j=1, j=3)
#pragma unroll
        for (int i = 0; i < 2; ++i)
#pragma unroll
            for (int r = 0; r < 4; ++r) {
                const long row = m0 + wm * 32 + i * 16 + quad * 4 + r;
                float sn, cs;
                sincosf((float)row * freq, &sn, &cs);
                const float x1 = acc[i][0][r], x2 = acc[i][2][r];
                bf16* p = dst + row * HD;
                p[d0]      = (bf16)((x1 * cs + x2 * sn) * sc);
                p[d0 + 64] = (bf16)((x2 * cs - x1 * sn) * sc);
                p[d1]      = (bf16)(acc[i][1][r] * sc);
                p[d1 + 64] = (bf16)(acc[i][3][r] * sc);
            }
    } else {                                           // V head: write V^T[d][l]
        bf16* dst = Vtb + (long)(head - 20) * HD * L_SEQ;
#pragma unroll
        for (int i = 0; i < 2; ++i) {
            const long m = m0 + wm * 32 + i * 16 + quad * 4;
#pragma unroll
            for (int j = 0; j < 4; ++j) {
                const int d = j * 32 + wn * 16 + l15;
                bf16x4v vv;
#pragma unroll
                for (int r = 0; r < 4; ++r) vv[r] = (bf16)acc[i][j][r];
                *(bf16x4v*)(dst + (long)d * L_SEQ + m) = vv;
            }
        }
    }
}

// ---------------------------------------------------------------------------
// gemm_out: 64Mx64N tile, BK=64 dbuf, 1 barrier/iter — gemm_qkv's proven
// template with only row counts changed. Grid (32,32) = 1024 blocks @ 32KB
// LDS = exactly 4 blocks/CU (old: 512 blocks = 2/CU, single-buffered,
// 2 barriers per BK=32 -> ~360 TF, worst of the three big kernels). GEMM
// blocks share operand panels (A+B = 16MB, L2/L3-resident) so the finer
// grid is locality-safe, unlike attn's disjoint KV streams (r2 lesson).
// ---------------------------------------------------------------------------
__global__ __launch_bounds__(256, 4) void gemm_out(const bf16* __restrict__ A,
                                                   const bf16* __restrict__ Bt,
                                                   float* __restrict__ C) {
    constexpr int KDIM = D_MODEL;
    __shared__ __align__(16) bf16 As[2][64 * 64];
    __shared__ __align__(16) bf16 Bs[2][64 * 64];
    const int tid = threadIdx.x;
    const int wid = tid >> 6, lane = tid & 63;
    const int quad = lane >> 4, l15 = lane & 15;
    const int wm = wid & 1, wn = wid >> 1;
    const long m0 = (long)blockIdx.y * 64, n0 = (long)blockIdx.x * 64;

    f32x4 acc[2][2];
#pragma unroll
    for (int i = 0; i < 2; ++i)
#pragma unroll
        for (int j = 0; j < 2; ++j) acc[i][j] = (f32x4){0.f, 0.f, 0.f, 0.f};

    const int srow8 = lane >> 3;
    const int schunk = lane & 7;

    auto stage = [&](int k0, int buf) {
#pragma unroll
        for (int ii = 0; ii < 2; ++ii) {     // A tile: 64 rows
            const int rowb = wid * 16 + ii * 8;
            const int row = rowb + srow8;
            const int gcol = (schunk ^ (row & 7)) * 8;
            GLD16(A + (m0 + row) * KDIM + k0 + gcol, &As[buf][rowb * 64]);
        }
#pragma unroll
        for (int ii = 0; ii < 2; ++ii) {     // B tile: 64 rows
            const int rowb = wid * 16 + ii * 8;
            const int row = rowb + srow8;
            const int gcol = (schunk ^ (row & 7)) * 8;
            GLD16(Bt + (n0 + row) * KDIM + k0 + gcol, &Bs[buf][rowb * 64]);
        }
    };
    stage(0, 0);

    for (int k0 = 0; k0 < KDIM; k0 += 64) {
        __syncthreads();
        if (k0 + 64 < KDIM) stage(k0 + 64, ((k0 >> 6) + 1) & 1);
        const int buf = (k0 >> 6) & 1;
#pragma unroll
        for (int ks = 0; ks < 2; ++ks) {
            const int pos = ((ks * 4 + quad) ^ (l15 & 7)) * 8;
            bf16x8 af[2], bfr[2];
#pragma unroll
            for (int i = 0; i < 2; ++i)
                af[i] = *(const bf16x8*)&As[buf][(wm * 32 + i * 16 + l15) * 64 + pos];
#pragma unroll
            for (int j = 0; j < 2; ++j)
                bfr[j] = *(const bf16x8*)&Bs[buf][(wn * 32 + j * 16 + l15) * 64 + pos];
#pragma unroll
            for (int i = 0; i < 2; ++i)
#pragma unroll
                for (int j = 0; j < 2; ++j)
                    acc[i][j] = __builtin_amdgcn_mfma_f32_16x16x32_bf16(af[i], bfr[j], acc[i][j], 0, 0, 0);
        }
    }

#pragma unroll
    for (int i = 0; i < 2; ++i)
#pragma unroll
        for (int j = 0; j < 2; ++j) {
            const long row = m0 + wm * 32 + i * 16 + quad * 4;
            const long col = n0 + wn * 32 + j * 16 + l15;
#pragma unroll
            for (int r = 0; r < 4; ++r)
                C[(row + r) * (long)D_MODEL + col] = acc[i][j][r];
        }
}

// ---------------------------------------------------------------------------
// GQA attention half-job kernel — EXACT r1 structure (proven 48.8-49.1us,
// 16.4MB fetch, VGPR 108). r5's setprio delta measured +3.4us (-7%): our
// 4-wave barrier-locked lockstep structure matches m190's GEMM null/negative
// case, not m191's independent-wave attn. FROZEN champion; no deltas.
// ---------------------------------------------------------------------------
__global__ __launch_bounds__(256, 2) void attn_p(const bf16* __restrict__ Qb,
                                                 const bf16* __restrict__ Kb,
                                                 const bf16* __restrict__ Vtb,
                                                 bf16* __restrict__ Opart,
                                                 float* __restrict__ lpart) {
    __shared__ __align__(1024) char smem[65536];

    const int bid = blockIdx.x;
    int t, hq, half;
    if (bid < 256) { t = bid >> 5; hq = (bid & 31) >> 1; half = bid & 1; }
    else { int b2 = bid - 256; t = 8 + (b2 >> 5); hq = (b2 & 31) >> 1; half = b2 & 1; }
    const int h = hq >> 2;
    const int q0 = t * 128;
    const int tid = threadIdx.x;
    const int w = tid >> 6;                  // wave 0..3, owns q rows w*32..+31
    const int lane = tid & 63;
    const int quad = lane >> 4, l15 = lane & 15;

    const bf16* Qg = Qb + (long)hq * L_SEQ * HD;
    const bf16* Kg = Kb + (long)h * L_SEQ * HD;
    const bf16* Vg = Vtb + (long)h * HD * L_SEQ;

    // Q as register B-frags
    bf16x8 qb[2][4];
#pragma unroll
    for (int rf = 0; rf < 2; ++rf)
#pragma unroll
        for (int kkd = 0; kkd < 4; ++kkd)
            qb[rf][kkd] = *(const bf16x8*)(Qg + (long)(q0 + w * 32 + rf * 16 + l15) * HD
                                              + kkd * 32 + quad * 8);

    f32x4 oaccT[2][8];
#pragma unroll
    for (int rf = 0; rf < 2; ++rf)
#pragma unroll
        for (int j = 0; j < 8; ++j) oaccT[rf][j] = (f32x4){0.f, 0.f, 0.f, 0.f};
    float lacc[2] = {0.f, 0.f};

    // valid 64-wide k-tiles: [0, locnt) U [2t, 32); n always even
    const int locnt = (2 * t - 14 > 0) ? (2 * t - 14) : 0;
    const int n = locnt + 32 - 2 * t;
    const int cnt = n >> 1;                  // this half-job's tile count

    auto ktile = [&](int idx) {
        const int i = 2 * idx + half;
        return (i < locnt) ? i : (2 * t + (i - locnt));
    };

    auto stage = [&](int idx, int buf) {
        const int k0 = ktile(idx) * 64;
        bf16* Ksb  = (bf16*)(smem + buf * 32768);
        bf16* Vtsb = (bf16*)(smem + buf * 32768 + 16384);
#pragma unroll
        for (int ii = 0; ii < 4; ++ii) {     // K tile: 64 keys x 128 d
            int rowb = w * 16 + ii * 4;
            int row = rowb + quad;
            GLD16(Kg + (long)(k0 + row) * HD + ((l15 ^ (row & 7)) * 8), &Ksb[rowb * 128]);
        }
#pragma unroll
        for (int ii = 0; ii < 4; ++ii) {     // V^T tile: 128 d x 64 keys
            int rowb = w * 32 + ii * 8;
            int row = rowb + (lane >> 3);
            GLD16(Vg + (long)row * L_SEQ + k0 + (((lane & 7) ^ (row & 7)) * 8), &Vtsb[rowb * 64]);
        }
    };

    stage(0, 0);

    for (int it = 0; it < cnt; ++it) {
        __syncthreads();                     // drains stage(it); prev reads done
        if (it + 1 < cnt) stage(it + 1, (it + 1) & 1);

        const int kt = ktile(it);
        const int k0 = kt * 64;
        const bf16* Ks  = (const bf16*)(smem + (it & 1) * 32768);
        const bf16* Vts = (const bf16*)(smem + (it & 1) * 32768 + 16384);

        // S^T = K Q^T : per wave 64 keys x 32 q
        f32x4 sacc[2][4];
#pragma unroll
        for (int kb = 0; kb < 4; ++kb) {
            bf16x8 ka[4];
#pragma unroll
            for (int kkd = 0; kkd < 4; ++kkd)
                ka[kkd] = *(const bf16x8*)&Ks[(kb * 16 + l15) * 128 +
                                              (((kkd * 4 + quad) ^ (l15 & 7)) * 8)];
#pragma unroll
            for (int rf = 0; rf < 2; ++rf) {
                f32x4 acc = (f32x4){0.f, 0.f, 0.f, 0.f};
#pragma unroll
                for (int kkd = 0; kkd < 4; ++kkd)
                    acc = __builtin_amdgcn_mfma_f32_16x16x32_bf16(ka[kkd], qb[rf][kkd], acc, 0, 0, 0);
                sacc[rf][kb] = acc;
            }
        }

        // mask boundary tiles + exp2 + pack P^T B-frags + l accumulate
        const bool bnd = (kt == 2 * t) || (kt == 2 * t + 1) ||
                         (kt == 2 * t - 15) || (kt == 2 * t - 16);
        s16x4 pb[2][4];
#pragma unroll
        for (int rf = 0; rf < 2; ++rf) {
            const int qq = q0 + w * 32 + rf * 16 + l15;
#pragma unroll
            for (int kb = 0; kb < 4; ++kb) {
#pragma unroll
                for (int r = 0; r < 4; ++r) {
                    float v = sacc[rf][kb][r];
                    if (bnd) {
                        const int kk = k0 + kb * 16 + quad * 4 + r;
                        if (!((kk > qq) || (kk <= qq - 1024))) v = -1e30f;
                    }
                    const float p = exp2f(v);
                    lacc[rf] += p;
                    bf16 hp = (bf16)p;
                    pb[rf][kb][r] = __builtin_bit_cast(short, hp);
                }
            }
        }

        // O^T += V^T P^T : 16x16x16 MFMA, A from LDS, B from registers
#pragma unroll
        for (int j = 0; j < 8; ++j) {
            const int drow = j * 16 + l15;
#pragma unroll
            for (int kq = 0; kq < 4; ++kq) {
                const int pc = ((kq * 2 + (quad >> 1)) ^ (l15 & 7));
                s16x4 va = *(const s16x4*)((const char*)&Vts[drow * 64] + pc * 16 + (quad & 1) * 8);
#pragma unroll
                for (int rf = 0; rf < 2; ++rf)
                    oaccT[rf][j] = __builtin_amdgcn_mfma_f32_16x16x16bf16_1k(
                        va, pb[rf][kq], oaccT[rf][j], 0, 0, 0);
            }
        }
    }

    // reduce l across quads (keys span quads)
#pragma unroll
    for (int rf = 0; rf < 2; ++rf) {
        lacc[rf] += __shfl_xor(lacc[rf], 16, 64);
        lacc[rf] += __shfl_xor(lacc[rf], 32, 64);
    }

    // write partials: Opart[bid][q 128][d 128] bf16, lpart[bid][q] f32
    bf16* Od = Opart + (long)bid * 16384;
#pragma unroll
    for (int rf = 0; rf < 2; ++rf) {
        const int ql = w * 32 + rf * 16 + l15;
#pragma unroll
        for (int j = 0; j < 8; ++j) {
            bf16x4v ov;
#pragma unroll
            for (int r = 0; r < 4; ++r) ov[r] = (bf16)oaccT[rf][j][r];
            *(bf16x4v*)(Od + ql * 128 + j * 16 + quad * 4) = ov;
        }
        if (quad == 0) lpart[bid * 128 + ql] = lacc[rf];
    }
}

// ---------------------------------------------------------------------------
// combine: attnb[q][hq*128+d] = (O0+O1) / (l0+l1+exp2(sink*log2e))
// ---------------------------------------------------------------------------
__global__ __launch_bounds__(256) void attn_combine(const bf16* __restrict__ Opart,
                                                    const float* __restrict__ lpart,
                                                    const float* __restrict__ sink,
                                                    bf16* __restrict__ attnb) {
    const int job = blockIdx.x >> 3, sub = blockIdx.x & 7;
    const int t = job >> 4, hq = job & 15;
    const int bid0 = (t < 8) ? (t * 32 + hq * 2) : (256 + (t - 8) * 32 + hq * 2);
    const int bid1 = bid0 + 1;
    const int e = sub * 2048 + threadIdx.x * 8;
    const int q = e >> 7, d0 = e & 127;
    bf16x8 o0 = *(const bf16x8*)(Opart + (long)bid0 * 16384 + q * 128 + d0);
    bf16x8 o1 = *(const bf16x8*)(Opart + (long)bid1 * 16384 + q * 128 + d0);
    const float l = lpart[bid0 * 128 + q] + lpart[bid1 * 128 + q] +
                    exp2f(sink[hq] * LOG2E);
    const float inv = 1.0f / l;
    bf16x8 ov;
#pragma unroll
    for (int r = 0; r < 8; ++r)
        ov[r] = (bf16)(((float)o0[r] + (float)o1[r]) * inv);
    *(bf16x8*)(attnb + (long)(t * 128 + q) * D_MODEL + hq * 128 + d0) = ov;
}

// ---------------------------------------------------------------------------
extern "C" void kernel_launch(void* const* d_in, const int* in_sizes, int n_in,
                              void* d_out, int out_size, void* d_ws, size_t ws_size,
                              hipStream_t stream) {
    (void)in_sizes; (void)n_in; (void)out_size; (void)ws_size;
    const float* x    = (const float*)d_in[0];
    const float* Wqkv = (const float*)d_in[1];
    const float* Wo   = (const float*)d_in[2];
    const float* s    = (const float*)d_in[3];
    float* out = (float*)d_out;

    // persistent layout (48 MB): [xb 8M][wqkvT 12.6M][Qb 8M][Kb 2M][Vtb 2M]
    //                            [woT 8M][attnb 8M]
    // Opart (16.8M bf16) + lpart (0.25M) alias [xb..wqkvT] (dead during attn).
    char* ws = (char*)d_ws;
    bf16* xb    = (bf16*)ws;
    bf16* wqkvT = (bf16*)(ws + 8388608);
    bf16* Qb    = (bf16*)(ws + 20971520);
    bf16* Kb    = (bf16*)(ws + 29360128);
    bf16* Vtb   = (bf16*)(ws + 31457280);
    bf16* woT   = (bf16*)(ws + 33554432);
    bf16* attnb = (bf16*)(ws + 41943040);
    bf16* Opart = (bf16*)ws;                  // 512 x 128 x 128 bf16
    float* lpart = (float*)(ws + 16777216);   // 512 x 128 f32

    prep<<<14336, 256, 0, stream>>>(x, Wqkv, Wo, xb, wqkvT, woT);

    gemm_qkv<<<dim3(QKV_N / 128, L_SEQ / 64), 256, 0, stream>>>(
        xb, wqkvT, Qb, Kb, Vtb);

    attn_p<<<512, 256, 0, stream>>>(Qb, Kb, Vtb, Opart, lpart);

    attn_combine<<<2048, 256, 0, stream>>>(Opart, lpart, s, attnb);

    gemm_out<<<dim3(D_MODEL / 64, L_SEQ / 64), 256, 0, stream>>>(
        attnb, woT, out);
}